// Round 1
// baseline (290.462 us; speedup 1.0000x reference)
//
#include <hip/hip_runtime.h>
#include <hip/hip_bf16.h>
#include <stdint.h>

#define T_TOK 2048
#define HDIM  1024
#define IDIM  768
#define NEXP  32
#define TOPK  4
#define NPAIR (T_TOK*TOPK)   // 8192

typedef __attribute__((ext_vector_type(8))) short bf16x8;
typedef __attribute__((ext_vector_type(4))) float f32x4;

__device__ __forceinline__ unsigned short f2bf(float f){
  union { float f; unsigned u; } v; v.f = f;
  unsigned r = (v.u + 0x7fffu + ((v.u >> 16) & 1u)) >> 16;  // RNE
  return (unsigned short)r;
}

// ---------------- x fp32 -> bf16 ----------------
__global__ __launch_bounds__(256) void k_convert_x(const float* __restrict__ x,
                                                   ushort* __restrict__ xb){
  int idx = blockIdx.x*256 + threadIdx.x;          // T*H/4 threads
  float4 v = ((const float4*)x)[idx];
  ushort4 o; o.x=f2bf(v.x); o.y=f2bf(v.y); o.z=f2bf(v.z); o.w=f2bf(v.w);
  ((ushort4*)xb)[idx] = o;
}

// ---------------- router: logits, exp, top-4, renorm ----------------
__global__ __launch_bounds__(256) void k_router(const float* __restrict__ x,
                                                const float* __restrict__ gw,
                                                int* __restrict__ ei, float* __restrict__ wv,
                                                int* __restrict__ counts){
  int wid  = threadIdx.x >> 6;
  int lane = threadIdx.x & 63;
  int t = blockIdx.x*4 + wid;
  float xv[16];
  #pragma unroll
  for (int i=0;i<16;i++) xv[i] = x[t*HDIM + i*64 + lane];
  float p[NEXP];
  #pragma unroll
  for (int e=0;e<NEXP;e++){
    const float* w = gw + e*HDIM;
    float a = 0.f;
    #pragma unroll
    for (int i=0;i<16;i++) a = fmaf(xv[i], w[i*64+lane], a);
    #pragma unroll
    for (int off=32; off>=1; off>>=1) a += __shfl_xor(a, off, 64);
    p[e] = a;
  }
  float m = p[0];
  #pragma unroll
  for (int e=1;e<NEXP;e++) m = fmaxf(m, p[e]);
  #pragma unroll
  for (int e=0;e<NEXP;e++) p[e] = __expf(p[e]-m);   // softmax denom cancels after renorm
  unsigned used = 0; int sel[TOPK]; float sw[TOPK]; float wsum = 0.f;
  #pragma unroll
  for (int k=0;k<TOPK;k++){
    float best = -1.f; int bi = 0;
    #pragma unroll
    for (int e=0;e<NEXP;e++){
      bool ok = (((used>>e)&1u)==0u) && (p[e] > best);  // strict > : ties pick lower idx (jax)
      best = ok ? p[e] : best; bi = ok ? e : bi;
    }
    used |= 1u<<bi; sel[k]=bi; sw[k]=best; wsum += best;
  }
  if (lane==0){
    float inv = 1.f/wsum;
    #pragma unroll
    for (int k=0;k<TOPK;k++){
      ei[t*TOPK+k] = sel[k];
      wv[t*TOPK+k] = sw[k]*inv;
      atomicAdd(&counts[sel[k]], 1);
    }
  }
}

// ---------------- prefix sum over 32 experts ----------------
__global__ void k_offsets(const int* __restrict__ counts, int* __restrict__ offsets){
  if (threadIdx.x==0 && blockIdx.x==0){
    int s=0;
    for (int e=0;e<NEXP;e++){ offsets[e]=s; s+=counts[e]; }
    offsets[NEXP]=s;
  }
}

// ---------------- scatter (t,k) -> slot grouped by expert ----------------
__global__ __launch_bounds__(256) void k_scatter(const int* __restrict__ ei,
                                                 const int* __restrict__ offsets,
                                                 int* __restrict__ cursor,
                                                 int* __restrict__ slot_tk,
                                                 int* __restrict__ tk_slot){
  int g = blockIdx.x*256 + threadIdx.x;            // 0..NPAIR-1
  int e = ei[g];
  int pos = atomicAdd(&cursor[e], 1);
  int slot = offsets[e] + pos;
  slot_tk[slot] = g;
  tk_slot[g] = slot;
}

// ---------------- gate+up GEMM + SiLU: act[slot][i] (bf16) ----------------
// block tile: M=256 (token slots), N=64 (i), BK=64; 8 waves (4m x 2n), wave 64x32
__global__ __launch_bounds__(512) void k_gateup(const ushort* __restrict__ xb,
    const float* __restrict__ w1, const float* __restrict__ w3,
    const int* __restrict__ offsets, const int* __restrict__ slot_tk,
    ushort* __restrict__ act){
  // XCD-locality remap: expert e -> XCD e%8 (assuming round-robin dispatch)
  int flat = blockIdx.x + 12*(blockIdx.y + 8*blockIdx.z);   // 0..3071
  int e    = (flat & 7) + 8*((flat>>3)&3);
  int rest = flat >> 5;                                     // 0..95
  int it   = rest % 12;                                     // i tile
  int mt   = rest / 12;                                     // m tile 0..7
  int off0 = offsets[e];
  int ne   = offsets[e+1]-off0;
  int m0   = mt*256;
  if (m0 >= ne) return;
  int ibase = it*64;

  __shared__ int toks[256];
  __shared__ ushort Als[256][72];      // +8 pad kills b128 bank conflicts
  __shared__ ushort Bls[2][64][72];

  int tid = threadIdx.x;
  if (tid < 256){
    int slot = off0 + m0 + tid;
    int fallback = slot_tk[off0] >> 2;
    toks[tid] = (m0 + tid < ne) ? (slot_tk[slot] >> 2) : fallback;
  }
  __syncthreads();

  int wid = tid >> 6, lane = tid & 63;
  int wm = wid >> 1, wn = wid & 1;
  f32x4 accg[4][2], accu[4][2];
  #pragma unroll
  for (int a=0;a<4;a++)
    #pragma unroll
    for (int b=0;b<2;b++){ accg[a][b]=(f32x4){0,0,0,0}; accu[a][b]=(f32x4){0,0,0,0}; }

  const size_t wbase = (size_t)e * IDIM * HDIM;
  for (int kb=0; kb<HDIM/64; ++kb){
    // stage A (gathered x rows, already bf16): 256x64
    #pragma unroll
    for (int s=0;s<4;s++){
      int li = s*512 + tid;            // 0..2047
      int row = li >> 3, c8 = li & 7;
      int tok = toks[row];
      int4 v = *(const int4*)(xb + (size_t)tok*HDIM + kb*64 + c8*8);
      *(int4*)(&Als[row][c8*8]) = v;
    }
    // stage B (w1,w3 fp32 -> bf16): 2 x 64x64
    #pragma unroll
    for (int mat=0; mat<2; ++mat){
      const float* wsrc = (mat ? w3 : w1) + wbase;
      #pragma unroll
      for (int s=0;s<2;s++){
        int li = s*512 + tid;          // 0..1023
        int row = li >> 4, c4 = li & 15;
        float4 f = *(const float4*)(wsrc + (size_t)(ibase+row)*HDIM + kb*64 + c4*4);
        ushort4 o; o.x=f2bf(f.x); o.y=f2bf(f.y); o.z=f2bf(f.z); o.w=f2bf(f.w);
        *(ushort4*)(&Bls[mat][row][c4*4]) = o;
      }
    }
    __syncthreads();
    #pragma unroll
    for (int kk=0; kk<2; ++kk){
      bf16x8 af[4];
      #pragma unroll
      for (int m=0;m<4;m++)
        af[m] = *(const bf16x8*)(&Als[wm*64 + m*16 + (lane&15)][kk*32 + (lane>>4)*8]);
      #pragma unroll
      for (int n=0;n<2;n++){
        bf16x8 bg = *(const bf16x8*)(&Bls[0][wn*32 + n*16 + (lane&15)][kk*32 + (lane>>4)*8]);
        bf16x8 bu = *(const bf16x8*)(&Bls[1][wn*32 + n*16 + (lane&15)][kk*32 + (lane>>4)*8]);
        #pragma unroll
        for (int m=0;m<4;m++){
          accg[m][n] = __builtin_amdgcn_mfma_f32_16x16x32_bf16(af[m], bg, accg[m][n], 0,0,0);
          accu[m][n] = __builtin_amdgcn_mfma_f32_16x16x32_bf16(af[m], bu, accu[m][n], 0,0,0);
        }
      }
    }
    __syncthreads();
  }
  int nval = ne - m0; if (nval > 256) nval = 256;
  #pragma unroll
  for (int m=0;m<4;m++)
    #pragma unroll
    for (int n=0;n<2;n++)
      #pragma unroll
      for (int r=0;r<4;r++){
        int row = wm*64 + m*16 + (lane>>4)*4 + r;   // D: row=(l>>4)*4+r, col=l&15
        if (row < nval){
          float g = accg[m][n][r], u = accu[m][n][r];
          float sval = g / (1.f + __expf(-g)) * u;  // silu(g)*u
          act[(size_t)(off0+m0+row)*IDIM + ibase + wn*32 + n*16 + (lane&15)] = f2bf(sval);
        }
      }
}

// ---------------- down GEMM: pout[slot][h] (fp32) ----------------
__global__ __launch_bounds__(512) void k_down(const ushort* __restrict__ act,
    const float* __restrict__ w2, const int* __restrict__ offsets,
    float* __restrict__ pout){
  int flat = blockIdx.x + 16*(blockIdx.y + 8*blockIdx.z);  // 0..4095
  int e    = (flat & 7) + 8*((flat>>3)&3);
  int rest = flat >> 5;                                    // 0..127
  int ht   = rest & 15;
  int mt   = rest >> 4;
  int off0 = offsets[e], ne = offsets[e+1]-off0;
  int m0   = mt*256;
  if (m0 >= ne) return;
  int hbase = ht*64;

  __shared__ ushort Als[256][72];
  __shared__ ushort Bls[64][72];

  int tid = threadIdx.x, wid = tid>>6, lane = tid&63;
  int wm = wid>>1, wn = wid&1;
  f32x4 acc[4][2];
  #pragma unroll
  for (int a=0;a<4;a++)
    #pragma unroll
    for (int b=0;b<2;b++) acc[a][b]=(f32x4){0,0,0,0};

  const size_t wbase = (size_t)e * HDIM * IDIM;
  for (int kb=0; kb<IDIM/64; ++kb){
    #pragma unroll
    for (int s=0;s<4;s++){
      int li = s*512+tid; int row = li>>3, c8 = li&7;
      int slot = off0 + m0 + row; slot = slot < NPAIR ? slot : NPAIR-1;
      int4 v = *(const int4*)(act + (size_t)slot*IDIM + kb*64 + c8*8);
      *(int4*)(&Als[row][c8*8]) = v;
    }
    #pragma unroll
    for (int s=0;s<2;s++){
      int li = s*512+tid; int row = li>>4, c4 = li&15;
      float4 f = *(const float4*)(w2 + wbase + (size_t)(hbase+row)*IDIM + kb*64 + c4*4);
      ushort4 o; o.x=f2bf(f.x); o.y=f2bf(f.y); o.z=f2bf(f.z); o.w=f2bf(f.w);
      *(ushort4*)(&Bls[row][c4*4]) = o;
    }
    __syncthreads();
    #pragma unroll
    for (int kk=0;kk<2;kk++){
      bf16x8 af[4];
      #pragma unroll
      for (int m=0;m<4;m++)
        af[m] = *(const bf16x8*)(&Als[wm*64 + m*16 + (lane&15)][kk*32 + (lane>>4)*8]);
      #pragma unroll
      for (int n=0;n<2;n++){
        bf16x8 bw = *(const bf16x8*)(&Bls[wn*32 + n*16 + (lane&15)][kk*32 + (lane>>4)*8]);
        #pragma unroll
        for (int m=0;m<4;m++)
          acc[m][n] = __builtin_amdgcn_mfma_f32_16x16x32_bf16(af[m], bw, acc[m][n], 0,0,0);
      }
    }
    __syncthreads();
  }
  int nval = ne - m0; if (nval > 256) nval = 256;
  #pragma unroll
  for (int m=0;m<4;m++)
    #pragma unroll
    for (int n=0;n<2;n++)
      #pragma unroll
      for (int r=0;r<4;r++){
        int row = wm*64 + m*16 + (lane>>4)*4 + r;
        if (row < nval)
          pout[(size_t)(off0+m0+row)*HDIM + hbase + wn*32 + n*16 + (lane&15)] = acc[m][n][r];
      }
}

// ---------------- combine: out[t] = sum_k w_k * pout[slot(t,k)] ----------------
__global__ __launch_bounds__(256) void k_combine(const float* __restrict__ pout,
    const int* __restrict__ tk_slot, const float* __restrict__ wv,
    float* __restrict__ out){
  int t = blockIdx.x;
  int c = threadIdx.x;                 // 0..255, 4 floats each
  float a0=0,a1=0,a2=0,a3=0;
  #pragma unroll
  for (int k=0;k<TOPK;k++){
    int slot = tk_slot[t*TOPK+k];
    float w  = wv[t*TOPK+k];
    float4 v = *(const float4*)(pout + (size_t)slot*HDIM + c*4);
    a0 = fmaf(w, v.x, a0); a1 = fmaf(w, v.y, a1);
    a2 = fmaf(w, v.z, a2); a3 = fmaf(w, v.w, a3);
  }
  float4 o; o.x=a0; o.y=a1; o.z=a2; o.w=a3;
  *(float4*)(out + (size_t)t*HDIM + c*4) = o;
}

extern "C" void kernel_launch(void* const* d_in, const int* in_sizes, int n_in,
                              void* d_out, int out_size, void* d_ws, size_t ws_size,
                              hipStream_t stream){
  const float* x  = (const float*)d_in[0];
  const float* gw = (const float*)d_in[1];
  const float* w1 = (const float*)d_in[2];   // w_gate [E,I,H]
  const float* w3 = (const float*)d_in[3];   // w_up   [E,I,H]
  const float* w2 = (const float*)d_in[4];   // w_down [E,H,I]
  float* out = (float*)d_out;

  char* ws = (char*)d_ws;
  size_t off = 0;
  ushort* xb   = (ushort*)(ws + off); off += (size_t)T_TOK*HDIM*2;   // 4 MB
  ushort* act  = (ushort*)(ws + off); off += (size_t)NPAIR*IDIM*2;   // 12.6 MB
  float*  pout = (float*) (ws + off); off += (size_t)NPAIR*HDIM*4;   // 33.6 MB
  int* counts  = (int*)(ws + off); off += NEXP*4;
  int* cursor  = (int*)(ws + off); off += NEXP*4;
  int* offsets = (int*)(ws + off); off += (NEXP+1)*4;
  off = (off + 255) & ~(size_t)255;
  int*   ei      = (int*)  (ws + off); off += (size_t)NPAIR*4;
  float* wvp     = (float*)(ws + off); off += (size_t)NPAIR*4;
  int*   slot_tk = (int*)  (ws + off); off += (size_t)NPAIR*4;
  int*   tk_slot = (int*)  (ws + off); off += (size_t)NPAIR*4;

  hipMemsetAsync(counts, 0, 2*NEXP*4, stream);   // zero counts + cursor

  k_convert_x<<<T_TOK*HDIM/1024, 256, 0, stream>>>(x, xb);
  k_router<<<T_TOK/4, 256, 0, stream>>>(x, gw, ei, wvp, counts);
  k_offsets<<<1, 64, 0, stream>>>(counts, offsets);
  k_scatter<<<NPAIR/256, 256, 0, stream>>>(ei, offsets, cursor, slot_tk, tk_slot);
  k_gateup<<<dim3(12,8,32), 512, 0, stream>>>(xb, w1, w3, offsets, slot_tk, act);
  k_down<<<dim3(16,8,32), 512, 0, stream>>>(act, w2, offsets, pout);
  k_combine<<<T_TOK, 256, 0, stream>>>(pout, tk_slot, wvp, out);
}

// Round 2
// 253.190 us; speedup vs baseline: 1.1472x; 1.1472x over previous
//
#include <hip/hip_runtime.h>
#include <hip/hip_bf16.h>
#include <stdint.h>

#define T_TOK 2048
#define HDIM  1024
#define IDIM  768
#define NEXP  32
#define TOPK  4
#define NPAIR (T_TOK*TOPK)   // 8192

typedef __attribute__((ext_vector_type(8))) short bf16x8;
typedef __attribute__((ext_vector_type(4))) float f32x4;

typedef __attribute__((address_space(1))) const unsigned int gu32;
typedef __attribute__((address_space(3))) unsigned int lu32;

__device__ __forceinline__ void gload_lds16(const void* g, void* l){
  __builtin_amdgcn_global_load_lds((gu32*)g, (lu32*)l, 16, 0, 0);
}

__device__ __forceinline__ unsigned short f2bf(float f){
  union { float f; unsigned u; } v; v.f = f;
  unsigned r = (v.u + 0x7fffu + ((v.u >> 16) & 1u)) >> 16;  // RNE
  return (unsigned short)r;
}

// ---------------- x fp32 -> bf16 ----------------
__global__ __launch_bounds__(256) void k_convert_x(const float* __restrict__ x,
                                                   ushort* __restrict__ xb){
  int idx = blockIdx.x*256 + threadIdx.x;
  float4 v = ((const float4*)x)[idx];
  ushort4 o; o.x=f2bf(v.x); o.y=f2bf(v.y); o.z=f2bf(v.z); o.w=f2bf(v.w);
  ((ushort4*)xb)[idx] = o;
}

// ---------------- router ----------------
__global__ __launch_bounds__(256) void k_router(const float* __restrict__ x,
                                                const float* __restrict__ gw,
                                                int* __restrict__ ei, float* __restrict__ wv,
                                                int* __restrict__ counts){
  int wid  = threadIdx.x >> 6;
  int lane = threadIdx.x & 63;
  int t = blockIdx.x*4 + wid;
  float xv[16];
  #pragma unroll
  for (int i=0;i<16;i++) xv[i] = x[t*HDIM + i*64 + lane];
  float p[NEXP];
  #pragma unroll
  for (int e=0;e<NEXP;e++){
    const float* w = gw + e*HDIM;
    float a = 0.f;
    #pragma unroll
    for (int i=0;i<16;i++) a = fmaf(xv[i], w[i*64+lane], a);
    #pragma unroll
    for (int off=32; off>=1; off>>=1) a += __shfl_xor(a, off, 64);
    p[e] = a;
  }
  float m = p[0];
  #pragma unroll
  for (int e=1;e<NEXP;e++) m = fmaxf(m, p[e]);
  #pragma unroll
  for (int e=0;e<NEXP;e++) p[e] = __expf(p[e]-m);
  unsigned used = 0; int sel[TOPK]; float sw[TOPK]; float wsum = 0.f;
  #pragma unroll
  for (int k=0;k<TOPK;k++){
    float best = -1.f; int bi = 0;
    #pragma unroll
    for (int e=0;e<NEXP;e++){
      bool ok = (((used>>e)&1u)==0u) && (p[e] > best);
      best = ok ? p[e] : best; bi = ok ? e : bi;
    }
    used |= 1u<<bi; sel[k]=bi; sw[k]=best; wsum += best;
  }
  if (lane==0){
    float inv = 1.f/wsum;
    #pragma unroll
    for (int k=0;k<TOPK;k++){
      ei[t*TOPK+k] = sel[k];
      wv[t*TOPK+k] = sw[k]*inv;
      atomicAdd(&counts[sel[k]], 1);
    }
  }
}

__global__ void k_offsets(const int* __restrict__ counts, int* __restrict__ offsets){
  if (threadIdx.x==0 && blockIdx.x==0){
    int s=0;
    for (int e=0;e<NEXP;e++){ offsets[e]=s; s+=counts[e]; }
    offsets[NEXP]=s;
  }
}

__global__ __launch_bounds__(256) void k_scatter(const int* __restrict__ ei,
                                                 const int* __restrict__ offsets,
                                                 int* __restrict__ cursor,
                                                 int* __restrict__ slot_tk,
                                                 int* __restrict__ tk_slot){
  int g = blockIdx.x*256 + threadIdx.x;
  int e = ei[g];
  int pos = atomicAdd(&cursor[e], 1);
  int slot = offsets[e] + pos;
  slot_tk[slot] = g;
  tk_slot[g] = slot;
}

// ---------------- gate+up GEMM + SiLU ----------------
// tile M=256 x N=96, BK=64, NKB=16; 8 waves (4m x 2n), wave 64x48
// A: global_load_lds (bf16) with XOR-swizzled source; B: reg-staged fp32->bf16
__global__ __launch_bounds__(512) void k_gateup(const ushort* __restrict__ xb,
    const float* __restrict__ w1, const float* __restrict__ w3,
    const int* __restrict__ offsets, const int* __restrict__ slot_tk,
    ushort* __restrict__ act){
  int flat = blockIdx.x;                         // 512 blocks; first 256 are mt=0
  int e    = (flat & 7) + 8*((flat>>3)&3);       // expert -> XCD e&7
  int it   = (flat>>5)&7;
  int mt   = flat>>8;
  int off0 = offsets[e];
  int ne   = offsets[e+1]-off0;
  int m0   = mt*256;
  if (m0 >= ne) return;
  int ibase = it*96;

  __shared__ int toks[256];
  __shared__ ushort Als[2][256][64];             // linear dest, swizzled content
  __shared__ ushort Bls[2][2][96][72];           // +8 pad

  int tid = threadIdx.x, wid = tid>>6, lane = tid&63;
  if (tid < 256){
    int slot = off0 + m0 + tid;
    int fb = slot_tk[off0] >> 2;
    toks[tid] = (m0 + tid < ne) ? (slot_tk[slot] >> 2) : fb;
  }
  __syncthreads();

  // per-lane A staging sources (source chunk pre-XOR'd so LDS reads are conflict-free)
  const ushort* asrc[4];
  int schunk = (lane&7) ^ (lane>>3);             // row&7 == lane>>3
  #pragma unroll
  for (int s=0;s<4;s++){
    int row = wid*32 + s*8 + (lane>>3);
    asrc[s] = xb + (size_t)toks[row]*HDIM + schunk*8;
  }
  // B staging source descriptors (6 float4/thread per K-step)
  const float* bsrc[6]; int b_mat[6], b_r[6], b_c4[6];
  const size_t wbase = (size_t)e * IDIM * HDIM;
  #pragma unroll
  for (int s=0;s<6;s++){
    int li = s*512 + tid;
    int mat = (li >= 1536) ? 1 : 0;
    int li2 = li - mat*1536;
    int r = li2>>4, c4 = li2&15;
    b_mat[s]=mat; b_r[s]=r; b_c4[s]=c4;
    bsrc[s] = (mat ? w3 : w1) + wbase + (size_t)(ibase+r)*HDIM + c4*4;
  }

  int wm = wid >> 1, wn = wid & 1;
  f32x4 accg[4][3], accu[4][3];
  #pragma unroll
  for (int a=0;a<4;a++)
    #pragma unroll
    for (int b=0;b<3;b++){ accg[a][b]=(f32x4){0,0,0,0}; accu[a][b]=(f32x4){0,0,0,0}; }

  float4 breg[6];
  // prologue: stage kb=0 into buf 0
  #pragma unroll
  for (int s=0;s<6;s++) breg[s] = *(const float4*)(bsrc[s]);
  #pragma unroll
  for (int s=0;s<4;s++) gload_lds16(asrc[s], &Als[0][wid*32+s*8][0]);
  #pragma unroll
  for (int s=0;s<6;s++){
    ushort4 o; o.x=f2bf(breg[s].x); o.y=f2bf(breg[s].y); o.z=f2bf(breg[s].z); o.w=f2bf(breg[s].w);
    *(ushort4*)(&Bls[0][b_mat[s]][b_r[s]][b_c4[s]*4]) = o;
  }
  __syncthreads();

  for (int kb=0; kb<16; ++kb){
    int cur = kb & 1, nxt = cur ^ 1;
    if (kb < 15){
      #pragma unroll
      for (int s=0;s<6;s++) breg[s] = *(const float4*)(bsrc[s] + (kb+1)*64);
      #pragma unroll
      for (int s=0;s<4;s++) gload_lds16(asrc[s] + (kb+1)*64, &Als[nxt][wid*32+s*8][0]);
    }
    // compute on cur
    #pragma unroll
    for (int kk=0; kk<2; ++kk){
      bf16x8 af[4];
      #pragma unroll
      for (int m=0;m<4;m++){
        int row = wm*64 + m*16 + (lane&15);
        int ch  = (kk*4 + (lane>>4)) ^ (lane&7);
        af[m] = *(const bf16x8*)(&Als[cur][row][ch*8]);
      }
      #pragma unroll
      for (int n=0;n<3;n++){
        bf16x8 bg = *(const bf16x8*)(&Bls[cur][0][wn*48 + n*16 + (lane&15)][kk*32 + (lane>>4)*8]);
        bf16x8 bu = *(const bf16x8*)(&Bls[cur][1][wn*48 + n*16 + (lane&15)][kk*32 + (lane>>4)*8]);
        #pragma unroll
        for (int m=0;m<4;m++){
          accg[m][n] = __builtin_amdgcn_mfma_f32_16x16x32_bf16(af[m], bg, accg[m][n], 0,0,0);
          accu[m][n] = __builtin_amdgcn_mfma_f32_16x16x32_bf16(af[m], bu, accu[m][n], 0,0,0);
        }
      }
    }
    if (kb < 15){
      #pragma unroll
      for (int s=0;s<6;s++){
        ushort4 o; o.x=f2bf(breg[s].x); o.y=f2bf(breg[s].y); o.z=f2bf(breg[s].z); o.w=f2bf(breg[s].w);
        *(ushort4*)(&Bls[nxt][b_mat[s]][b_r[s]][b_c4[s]*4]) = o;
      }
    }
    __syncthreads();
  }

  int nval = ne - m0; if (nval > 256) nval = 256;
  #pragma unroll
  for (int m=0;m<4;m++)
    #pragma unroll
    for (int n=0;n<3;n++)
      #pragma unroll
      for (int r=0;r<4;r++){
        int row = wm*64 + m*16 + (lane>>4)*4 + r;
        if (row < nval){
          float g = accg[m][n][r], u = accu[m][n][r];
          float sval = g / (1.f + __expf(-g)) * u;
          act[(size_t)(off0+m0+row)*IDIM + ibase + wn*48 + n*16 + (lane&15)] = f2bf(sval);
        }
      }
}

// ---------------- down GEMM ----------------
// tile M=256 x N=128, BK=64, NKB=12; 8 waves (4m x 2n), wave 64x64
__global__ __launch_bounds__(512) void k_down(const ushort* __restrict__ act,
    const float* __restrict__ w2, const int* __restrict__ offsets,
    float* __restrict__ pout){
  int flat = blockIdx.x;                         // 512 blocks
  int e    = (flat & 7) + 8*((flat>>3)&3);
  int ht   = (flat>>5)&7;
  int mt   = flat>>8;
  int off0 = offsets[e], ne = offsets[e+1]-off0;
  int m0   = mt*256;
  if (m0 >= ne) return;
  int hbase = ht*128;

  __shared__ ushort Als[2][256][64];
  __shared__ ushort Bls[2][128][72];

  int tid = threadIdx.x, wid = tid>>6, lane = tid&63;
  int wm = wid>>1, wn = wid&1;

  const ushort* asrc[4];
  int schunk = (lane&7) ^ (lane>>3);
  #pragma unroll
  for (int s=0;s<4;s++){
    int row = wid*32 + s*8 + (lane>>3);
    int mrow = m0 + row; mrow = (mrow < ne) ? mrow : (ne-1);
    asrc[s] = act + (size_t)(off0+mrow)*IDIM + schunk*8;
  }
  const float* bsrc[4]; int b_r[4], b_c4[4];
  const size_t wbase = (size_t)e * HDIM * IDIM;
  #pragma unroll
  for (int s=0;s<4;s++){
    int li = s*512 + tid;
    int r = li>>4, c4 = li&15;
    b_r[s]=r; b_c4[s]=c4;
    bsrc[s] = w2 + wbase + (size_t)(hbase+r)*IDIM + c4*4;
  }

  f32x4 acc[4][4];
  #pragma unroll
  for (int a=0;a<4;a++)
    #pragma unroll
    for (int b=0;b<4;b++) acc[a][b]=(f32x4){0,0,0,0};

  float4 breg[4];
  #pragma unroll
  for (int s=0;s<4;s++) breg[s] = *(const float4*)(bsrc[s]);
  #pragma unroll
  for (int s=0;s<4;s++) gload_lds16(asrc[s], &Als[0][wid*32+s*8][0]);
  #pragma unroll
  for (int s=0;s<4;s++){
    ushort4 o; o.x=f2bf(breg[s].x); o.y=f2bf(breg[s].y); o.z=f2bf(breg[s].z); o.w=f2bf(breg[s].w);
    *(ushort4*)(&Bls[0][b_r[s]][b_c4[s]*4]) = o;
  }
  __syncthreads();

  for (int kb=0; kb<12; ++kb){
    int cur = kb & 1, nxt = cur ^ 1;
    if (kb < 11){
      #pragma unroll
      for (int s=0;s<4;s++) breg[s] = *(const float4*)(bsrc[s] + (kb+1)*64);
      #pragma unroll
      for (int s=0;s<4;s++) gload_lds16(asrc[s] + (kb+1)*64, &Als[nxt][wid*32+s*8][0]);
    }
    #pragma unroll
    for (int kk=0; kk<2; ++kk){
      bf16x8 af[4];
      #pragma unroll
      for (int m=0;m<4;m++){
        int row = wm*64 + m*16 + (lane&15);
        int ch  = (kk*4 + (lane>>4)) ^ (lane&7);
        af[m] = *(const bf16x8*)(&Als[cur][row][ch*8]);
      }
      #pragma unroll
      for (int n=0;n<4;n++){
        bf16x8 bw = *(const bf16x8*)(&Bls[cur][wn*64 + n*16 + (lane&15)][kk*32 + (lane>>4)*8]);
        #pragma unroll
        for (int m=0;m<4;m++)
          acc[m][n] = __builtin_amdgcn_mfma_f32_16x16x32_bf16(af[m], bw, acc[m][n], 0,0,0);
      }
    }
    if (kb < 11){
      #pragma unroll
      for (int s=0;s<4;s++){
        ushort4 o; o.x=f2bf(breg[s].x); o.y=f2bf(breg[s].y); o.z=f2bf(breg[s].z); o.w=f2bf(breg[s].w);
        *(ushort4*)(&Bls[nxt][b_r[s]][b_c4[s]*4]) = o;
      }
    }
    __syncthreads();
  }

  int nval = ne - m0; if (nval > 256) nval = 256;
  #pragma unroll
  for (int m=0;m<4;m++)
    #pragma unroll
    for (int n=0;n<4;n++)
      #pragma unroll
      for (int r=0;r<4;r++){
        int row = wm*64 + m*16 + (lane>>4)*4 + r;
        if (row < nval)
          pout[(size_t)(off0+m0+row)*HDIM + hbase + wn*64 + n*16 + (lane&15)] = acc[m][n][r];
      }
}

// ---------------- combine ----------------
__global__ __launch_bounds__(256) void k_combine(const float* __restrict__ pout,
    const int* __restrict__ tk_slot, const float* __restrict__ wv,
    float* __restrict__ out){
  int t = blockIdx.x;
  int c = threadIdx.x;
  float a0=0,a1=0,a2=0,a3=0;
  #pragma unroll
  for (int k=0;k<TOPK;k++){
    int slot = tk_slot[t*TOPK+k];
    float w  = wv[t*TOPK+k];
    float4 v = *(const float4*)(pout + (size_t)slot*HDIM + c*4);
    a0 = fmaf(w, v.x, a0); a1 = fmaf(w, v.y, a1);
    a2 = fmaf(w, v.z, a2); a3 = fmaf(w, v.w, a3);
  }
  float4 o; o.x=a0; o.y=a1; o.z=a2; o.w=a3;
  *(float4*)(out + (size_t)t*HDIM + c*4) = o;
}

extern "C" void kernel_launch(void* const* d_in, const int* in_sizes, int n_in,
                              void* d_out, int out_size, void* d_ws, size_t ws_size,
                              hipStream_t stream){
  const float* x  = (const float*)d_in[0];
  const float* gw = (const float*)d_in[1];
  const float* w1 = (const float*)d_in[2];
  const float* w3 = (const float*)d_in[3];
  const float* w2 = (const float*)d_in[4];
  float* out = (float*)d_out;

  char* ws = (char*)d_ws;
  size_t off = 0;
  ushort* xb   = (ushort*)(ws + off); off += (size_t)T_TOK*HDIM*2;
  ushort* act  = (ushort*)(ws + off); off += (size_t)NPAIR*IDIM*2;
  float*  pout = (float*) (ws + off); off += (size_t)NPAIR*HDIM*4;
  int* counts  = (int*)(ws + off); off += NEXP*4;
  int* cursor  = (int*)(ws + off); off += NEXP*4;
  int* offsets = (int*)(ws + off); off += (NEXP+1)*4;
  off = (off + 255) & ~(size_t)255;
  int*   ei      = (int*)  (ws + off); off += (size_t)NPAIR*4;
  float* wvp     = (float*)(ws + off); off += (size_t)NPAIR*4;
  int*   slot_tk = (int*)  (ws + off); off += (size_t)NPAIR*4;
  int*   tk_slot = (int*)  (ws + off); off += (size_t)NPAIR*4;

  hipMemsetAsync(counts, 0, 2*NEXP*4, stream);

  k_convert_x<<<T_TOK*HDIM/1024, 256, 0, stream>>>(x, xb);
  k_router<<<T_TOK/4, 256, 0, stream>>>(x, gw, ei, wvp, counts);
  k_offsets<<<1, 64, 0, stream>>>(counts, offsets);
  k_scatter<<<NPAIR/256, 256, 0, stream>>>(ei, offsets, cursor, slot_tk, tk_slot);
  k_gateup<<<512, 512, 0, stream>>>(xb, w1, w3, offsets, slot_tk, act);
  k_down<<<512, 512, 0, stream>>>(act, w2, offsets, pout);
  k_combine<<<T_TOK, 256, 0, stream>>>(pout, tk_slot, wvp, out);
}